// Round 25
// baseline (10208.521 us; speedup 1.0000x reference)
//
#include <hip/hip_runtime.h>

#define NPTS   262144
#define DIM    128
#define DIM4   32
#define KC     102
#define NITERS 10
#define NBLK_H 512
#define CHK    512

// Reference model (identified r18-r23, bit-exact PASS r21/r23/r24):
//   x_sq/csq: numpy pairwise 8-acc tree, materialized squares
//   dot:      2-acc even/odd k-split FMA chains, D = fl(t0+t1)
//   d2:       fl(x_sq - 2D) + csq (two roundings); first-min argmin
//   segsum:   ascending-p sequential f32 adds per (cluster,dim); f32 divide
//   where:    empty cluster keeps old centroid

// ws layout (bytes)
#define WS_CA    0         // 53248
#define WS_CB    53248     // 53248
#define WS_CSQ   106496    // 1024
#define WS_CNT   107520    // 1024
#define WS_CBASE 108544    // 1024
#define WS_H     109568    // 208896
#define WS_OFFS  318464    // 208896
#define WS_PT    527360    // 1048576
#define WS_SMALL 1575936
#define WS_XG    2097152   // 128MB gathered copy (aligned)
#define WS_BIG   (WS_XG + (size_t)NPTS * DIM * 4)

__global__ void k_fill(int* __restrict__ p, int n, int v)
{
    const int i = blockIdx.x * 256 + threadIdx.x;
    if (i < n) p[i] = v;
}

// numpy pairwise tree, n=128 (8 accumulators, materialized squares)
__device__ __forceinline__ float np_sumsq128(const float* a)
{
#pragma clang fp contract(off)
    float r[8];
    #pragma unroll
    for (int t = 0; t < 8; ++t) { const float v = a[t]; r[t] = v * v; }
    #pragma unroll
    for (int i = 8; i < 128; i += 8) {
        #pragma unroll
        for (int t = 0; t < 8; ++t) { const float v = a[i + t]; r[t] += v * v; }
    }
    return ((r[0] + r[1]) + (r[2] + r[3])) + ((r[4] + r[5]) + (r[6] + r[7]));
}

__device__ __forceinline__ float xr_get(const float4* xr, int i)
{
    const float4 v = xr[i >> 2];
    const int c = i & 3;
    return c == 0 ? v.x : c == 1 ? v.y : c == 2 ? v.z : v.w;
}

__device__ __forceinline__ float np_sumsq128_reg(const float4* xr)
{
#pragma clang fp contract(off)
    float r[8];
    #pragma unroll
    for (int t = 0; t < 8; ++t) { const float v = xr_get(xr, t); r[t] = v * v; }
    #pragma unroll
    for (int i = 8; i < 128; i += 8) {
        #pragma unroll
        for (int t = 0; t < 8; ++t) { const float v = xr_get(xr, i + t); r[t] += v * v; }
    }
    return ((r[0] + r[1]) + (r[2] + r[3])) + ((r[4] + r[5]) + (r[6] + r[7]));
}

__global__ __launch_bounds__(128)
void k_initc(const float* __restrict__ x, float* __restrict__ c, float* __restrict__ csq)
{
    __shared__ float row[DIM];
    const int j = blockIdx.x, d = threadIdx.x;
    const float v = x[(size_t)j * DIM + d];
    c[j * DIM + d] = v;
    row[d] = v;
    __syncthreads();
    if (d == 0) csq[j] = np_sumsq128(row);
}

// fast f32 4-chain scan + exact-reference rescue
__global__ __launch_bounds__(256, 2)
void k_assign(const float* __restrict__ x, const float* __restrict__ c,
              const float* __restrict__ csq, int* __restrict__ labels)
{
    __shared__ float4 cl[KC * DIM4];
    __shared__ float  sj[KC];
    for (int i = threadIdx.x; i < KC * DIM4; i += 256)
        cl[i] = reinterpret_cast<const float4*>(c)[i];
    for (int i = threadIdx.x; i < KC; i += 256) sj[i] = csq[i];
    __syncthreads();

    const int p = blockIdx.x * 256 + threadIdx.x;
    const float4* xp = reinterpret_cast<const float4*>(x) + (size_t)p * DIM4;
    float4 xr[DIM4];
    #pragma unroll
    for (int q = 0; q < DIM4; ++q) xr[q] = xp[q];

    float best1 = 3.4e38f, best2 = 3.4e38f;
    int bi = 0;
    for (int j = 0; j < KC; ++j) {
        const float4* cj = &cl[j * DIM4];
        float a0 = 0.f, a1 = 0.f, a2 = 0.f, a3 = 0.f;
        #pragma unroll
        for (int q = 0; q < DIM4; ++q) {
            const float4 cv = cj[q];
            a0 = __builtin_fmaf(xr[q].x, cv.x, a0);
            a1 = __builtin_fmaf(xr[q].y, cv.y, a1);
            a2 = __builtin_fmaf(xr[q].z, cv.z, a2);
            a3 = __builtin_fmaf(xr[q].w, cv.w, a3);
        }
        const float F = sj[j] - 2.0f * ((a0 + a1) + (a2 + a3));
        if (F < best1)      { best2 = best1; best1 = F; bi = j; }
        else if (F < best2) { best2 = F; }
    }

    int lab = bi;
    if (best2 - best1 < 0.02f) {
        const float Tp  = np_sumsq128_reg(xr);
        const float win = best1 + 0.02f;
        float bestE = 3.4e38f;
        int bj = bi;
        for (int j = 0; j < KC; ++j) {
            const float4* cj = &cl[j * DIM4];
            float a0 = 0.f, a1 = 0.f, a2 = 0.f, a3 = 0.f;
            #pragma unroll
            for (int q = 0; q < DIM4; ++q) {
                const float4 cv = cj[q];
                a0 = __builtin_fmaf(xr[q].x, cv.x, a0);
                a1 = __builtin_fmaf(xr[q].y, cv.y, a1);
                a2 = __builtin_fmaf(xr[q].z, cv.z, a2);
                a3 = __builtin_fmaf(xr[q].w, cv.w, a3);
            }
            const float F = sj[j] - 2.0f * ((a0 + a1) + (a2 + a3));
            if (F <= win) {
                float t0 = 0.f, t1 = 0.f;
                #pragma unroll
                for (int q = 0; q < DIM4; ++q) {
                    const float4 cv = cj[q];
                    t0 = __builtin_fmaf(xr[q].x, cv.x, t0);
                    t1 = __builtin_fmaf(xr[q].y, cv.y, t1);
                    t0 = __builtin_fmaf(xr[q].z, cv.z, t0);
                    t1 = __builtin_fmaf(xr[q].w, cv.w, t1);
                }
                float E;
                {
#pragma clang fp contract(off)
                    const float D = t0 + t1;
                    const float u = Tp - 2.0f * D;
                    E = u + sj[j];
                }
                if (E < bestE) { bestE = E; bj = j; }
            }
        }
        lab = bj;
    }
    labels[p] = lab;
}

__global__ __launch_bounds__(256)
void k_hist(const int* __restrict__ labels, int* __restrict__ H)
{
    __shared__ int h[KC];
    for (int i = threadIdx.x; i < KC; i += 256) h[i] = 0;
    __syncthreads();
    const int b = blockIdx.x;
    #pragma unroll
    for (int u = 0; u < 2; ++u)
        atomicAdd(&h[labels[b * CHK + u * 256 + threadIdx.x]], 1);
    __syncthreads();
    for (int i = threadIdx.x; i < KC; i += 256) H[i * NBLK_H + b] = h[i];
}

__global__ __launch_bounds__(128)
void k_scan(const int* __restrict__ H, int* __restrict__ OFFS,
            int* __restrict__ counts, int* __restrict__ cbase)
{
    __shared__ int tot[KC];
    const int j = threadIdx.x;
    if (j < KC) {
        int run = 0;
        for (int b = 0; b < NBLK_H; ++b) { OFFS[j * NBLK_H + b] = run; run += H[j * NBLK_H + b]; }
        tot[j] = run;
    }
    __syncthreads();
    if (j == 0) {
        int base = 0;
        for (int jj = 0; jj < KC; ++jj) { cbase[jj] = base; counts[jj] = tot[jj]; base += tot[jj]; }
    }
}

// stable scatter: serial lane preserves ascending-p order within block
__global__ __launch_bounds__(64)
void k_scatter(const int* __restrict__ labels, const int* __restrict__ OFFS,
               const int* __restrict__ cbase, int* __restrict__ ptidx)
{
    __shared__ int lab[CHK];
    __shared__ int lrank[KC];
    __shared__ int soff[KC];
    const int b = blockIdx.x;
    for (int i = threadIdx.x; i < CHK; i += 64) lab[i] = labels[b * CHK + i];
    for (int i = threadIdx.x; i < KC; i += 64) { lrank[i] = 0; soff[i] = cbase[i] + OFFS[i * NBLK_H + b]; }
    __syncthreads();
    if (threadIdx.x == 0) {
        for (int i = 0; i < CHK; ++i) {
            const int l = lab[i];
            ptidx[soff[l] + lrank[l]++] = b * CHK + i;
        }
    }
}

// massively parallel stable gather: xg[i][*] = x[ptidx[i]][*]
// 8 rows/block, float4 lanes; reads 128B bursts, writes fully coalesced.
__global__ __launch_bounds__(256)
void k_gather(const float* __restrict__ x, const int* __restrict__ ptidx,
              float* __restrict__ xg)
{
    const int i = blockIdx.x * 8 + (threadIdx.x >> 5);
    const int q = threadIdx.x & 31;
    const int p = ptidx[i];
    reinterpret_cast<float4*>(xg)[(size_t)i * DIM4 + q] =
        reinterpret_cast<const float4*>(x)[(size_t)p * DIM4 + q];
}

// linear-stream exact update: double-buffered 32-row LDS tile, conflict-free
// column reads; per-lane ascending sequential f32 adds (bit-exact chain).
__global__ __launch_bounds__(128)
void k_update_lin(const float* __restrict__ xg, const int* __restrict__ counts,
                  const int* __restrict__ cbase, const float* __restrict__ cold,
                  float* __restrict__ cnew, float* __restrict__ csq)
{
    __shared__ float buf[2][32][DIM];   // 2 x 16KB
    __shared__ float row[DIM];
    const int j = blockIdx.x, d = threadIdx.x;
    const int n = counts[j];
    const size_t rowbase = (size_t)cbase[j];

    const int nc = (n + 31) >> 5;

    // stage chunk c into buffer b (cnt rows)
    auto stage = [&](int b, int r0, int cnt) {
        const float4* src = reinterpret_cast<const float4*>(xg) + (rowbase + r0) * DIM4;
        float4* dst = reinterpret_cast<float4*>(&buf[b][0][0]);
        for (int i = d; i < cnt * DIM4; i += 128) dst[i] = src[i];
    };

    float s = 0.f;
    if (n > 0) {
        stage(0, 0, min(32, n));
        __syncthreads();
        for (int c = 0; c < nc; ++c) {
            const int m = min(32, n - c * 32);
            if (c + 1 < nc) stage((c + 1) & 1, (c + 1) * 32, min(32, n - (c + 1) * 32));
            {
#pragma clang fp contract(off)
                const float* col = &buf[c & 1][0][d];
                for (int r = 0; r < m; ++r) s += col[(size_t)r * DIM];
            }
            __syncthreads();
        }
    }

    const float v = (n > 0) ? (s / fmaxf((float)n, 1.0f)) : cold[j * DIM + d];
    cnew[j * DIM + d] = v;
    row[d] = v;
    __syncthreads();
    if (d == 0) csq[j] = np_sumsq128(row);
}

// fallback update (r24 version) for small ws
__global__ __launch_bounds__(128)
void k_update(const float* __restrict__ x, const int* __restrict__ ptidx,
              const int* __restrict__ counts, const int* __restrict__ cbase,
              const float* __restrict__ cold, float* __restrict__ cnew,
              float* __restrict__ csq)
{
    __shared__ int   spt[CHK];
    __shared__ float row[DIM];
    const int j = blockIdx.x, d = threadIdx.x;
    const int n = counts[j], base = cbase[j];

    float s = 0.f;
    for (int c0 = 0; c0 < n; c0 += CHK) {
        const int m = min(CHK, n - c0);
        __syncthreads();
        for (int i = d; i < m; i += 128) spt[i] = ptidx[base + c0 + i];
        __syncthreads();
        {
#pragma clang fp contract(off)
            for (int t = 0; t < m; ++t) s += x[(size_t)spt[t] * DIM + d];
        }
    }

    const float v = (n > 0) ? (s / fmaxf((float)n, 1.0f)) : cold[j * DIM + d];
    cnew[j * DIM + d] = v;
    row[d] = v;
    __syncthreads();
    if (d == 0) csq[j] = np_sumsq128(row);
}

extern "C" void kernel_launch(void* const* d_in, const int* in_sizes, int n_in,
                              void* d_out, int out_size, void* d_ws, size_t ws_size,
                              hipStream_t stream)
{
    int* labels = (int*)d_out;

    const float* x = nullptr;
    for (int i = 0; i < n_in; ++i)
        if (in_sizes[i] == NPTS * DIM) { x = (const float*)d_in[i]; break; }
    if (!x)                         { k_fill<<<(NPTS+255)/256, 256, 0, stream>>>(labels, NPTS, 2000); return; }
    if (ws_size < (size_t)WS_SMALL) { k_fill<<<(NPTS+255)/256, 256, 0, stream>>>(labels, NPTS, 3000); return; }

    const bool big = ws_size >= (size_t)WS_BIG;

    char* w = (char*)d_ws;
    float* c_a    = (float*)(w + WS_CA);
    float* c_b    = (float*)(w + WS_CB);
    float* csq    = (float*)(w + WS_CSQ);
    int*   counts = (int*)  (w + WS_CNT);
    int*   cbase  = (int*)  (w + WS_CBASE);
    int*   H      = (int*)  (w + WS_H);
    int*   OFFS   = (int*)  (w + WS_OFFS);
    int*   ptidx  = (int*)  (w + WS_PT);
    float* xg     = (float*)(w + WS_XG);

    k_initc<<<KC, 128, 0, stream>>>(x, c_a, csq);

    float* c_cur = c_a;
    float* c_nxt = c_b;
    for (int it = 0; it < NITERS; ++it) {
        k_assign<<<NPTS / 256, 256, 0, stream>>>(x, c_cur, csq, labels);
        if (it < NITERS - 1) {
            k_hist   <<<NBLK_H, 256, 0, stream>>>(labels, H);
            k_scan   <<<1, 128, 0, stream>>>(H, OFFS, counts, cbase);
            k_scatter<<<NBLK_H, 64, 0, stream>>>(labels, OFFS, cbase, ptidx);
            if (big) {
                k_gather    <<<NPTS / 8, 256, 0, stream>>>(x, ptidx, xg);
                k_update_lin<<<KC, 128, 0, stream>>>(xg, counts, cbase, c_cur, c_nxt, csq);
            } else {
                k_update    <<<KC, 128, 0, stream>>>(x, ptidx, counts, cbase, c_cur, c_nxt, csq);
            }
            float* tmp = c_cur; c_cur = c_nxt; c_nxt = tmp;
        }
    }
}

// Round 26
// 6161.001 us; speedup vs baseline: 1.6570x; 1.6570x over previous
//
#include <hip/hip_runtime.h>

#define NPTS   262144
#define DIM    128
#define DIM4   32
#define KC     102
#define NITERS 10
#define NBLK_H 512
#define CHK    512

// Reference model (identified r18-r23, bit-exact PASS r21/r23/r24/r25):
//   x_sq/csq: numpy pairwise 8-acc tree, materialized squares
//   dot:      2-acc even/odd k-split FMA chains, D = fl(t0+t1)
//   d2:       fl(x_sq - 2D) + csq (two roundings); first-min argmin
//   segsum:   ascending-p sequential f32 adds per (cluster,dim); f32 divide
//   where:    empty cluster keeps old centroid

// ws layout (bytes)
#define WS_CA    0         // 53248
#define WS_CB    53248     // 53248
#define WS_CSQ   106496    // 1024
#define WS_CNT   107520    // 1024
#define WS_CBASE 108544    // 1024
#define WS_H     109568    // 208896
#define WS_OFFS  318464    // 208896
#define WS_PT    527360    // 1048576
#define WS_NEED  1575936

__global__ void k_fill(int* __restrict__ p, int n, int v)
{
    const int i = blockIdx.x * 256 + threadIdx.x;
    if (i < n) p[i] = v;
}

// numpy pairwise tree, n=128 (8 accumulators, materialized squares)
__device__ __forceinline__ float np_sumsq128(const float* a)
{
#pragma clang fp contract(off)
    float r[8];
    #pragma unroll
    for (int t = 0; t < 8; ++t) { const float v = a[t]; r[t] = v * v; }
    #pragma unroll
    for (int i = 8; i < 128; i += 8) {
        #pragma unroll
        for (int t = 0; t < 8; ++t) { const float v = a[i + t]; r[t] += v * v; }
    }
    return ((r[0] + r[1]) + (r[2] + r[3])) + ((r[4] + r[5]) + (r[6] + r[7]));
}

__device__ __forceinline__ float xr_get(const float4* xr, int i)
{
    const float4 v = xr[i >> 2];
    const int c = i & 3;
    return c == 0 ? v.x : c == 1 ? v.y : c == 2 ? v.z : v.w;
}

__device__ __forceinline__ float np_sumsq128_reg(const float4* xr)
{
#pragma clang fp contract(off)
    float r[8];
    #pragma unroll
    for (int t = 0; t < 8; ++t) { const float v = xr_get(xr, t); r[t] = v * v; }
    #pragma unroll
    for (int i = 8; i < 128; i += 8) {
        #pragma unroll
        for (int t = 0; t < 8; ++t) { const float v = xr_get(xr, i + t); r[t] += v * v; }
    }
    return ((r[0] + r[1]) + (r[2] + r[3])) + ((r[4] + r[5]) + (r[6] + r[7]));
}

__global__ __launch_bounds__(128)
void k_initc(const float* __restrict__ x, float* __restrict__ c, float* __restrict__ csq)
{
    __shared__ float row[DIM];
    const int j = blockIdx.x, d = threadIdx.x;
    const float v = x[(size_t)j * DIM + d];
    c[j * DIM + d] = v;
    row[d] = v;
    __syncthreads();
    if (d == 0) csq[j] = np_sumsq128(row);
}

// fast f32 4-chain scan + exact-reference rescue
__global__ __launch_bounds__(256, 2)
void k_assign(const float* __restrict__ x, const float* __restrict__ c,
              const float* __restrict__ csq, int* __restrict__ labels)
{
    __shared__ float4 cl[KC * DIM4];
    __shared__ float  sj[KC];
    for (int i = threadIdx.x; i < KC * DIM4; i += 256)
        cl[i] = reinterpret_cast<const float4*>(c)[i];
    for (int i = threadIdx.x; i < KC; i += 256) sj[i] = csq[i];
    __syncthreads();

    const int p = blockIdx.x * 256 + threadIdx.x;
    const float4* xp = reinterpret_cast<const float4*>(x) + (size_t)p * DIM4;
    float4 xr[DIM4];
    #pragma unroll
    for (int q = 0; q < DIM4; ++q) xr[q] = xp[q];

    float best1 = 3.4e38f, best2 = 3.4e38f;
    int bi = 0;
    for (int j = 0; j < KC; ++j) {
        const float4* cj = &cl[j * DIM4];
        float a0 = 0.f, a1 = 0.f, a2 = 0.f, a3 = 0.f;
        #pragma unroll
        for (int q = 0; q < DIM4; ++q) {
            const float4 cv = cj[q];
            a0 = __builtin_fmaf(xr[q].x, cv.x, a0);
            a1 = __builtin_fmaf(xr[q].y, cv.y, a1);
            a2 = __builtin_fmaf(xr[q].z, cv.z, a2);
            a3 = __builtin_fmaf(xr[q].w, cv.w, a3);
        }
        const float F = sj[j] - 2.0f * ((a0 + a1) + (a2 + a3));
        if (F < best1)      { best2 = best1; best1 = F; bi = j; }
        else if (F < best2) { best2 = F; }
    }

    int lab = bi;
    if (best2 - best1 < 0.02f) {
        const float Tp  = np_sumsq128_reg(xr);
        const float win = best1 + 0.02f;
        float bestE = 3.4e38f;
        int bj = bi;
        for (int j = 0; j < KC; ++j) {
            const float4* cj = &cl[j * DIM4];
            float a0 = 0.f, a1 = 0.f, a2 = 0.f, a3 = 0.f;
            #pragma unroll
            for (int q = 0; q < DIM4; ++q) {
                const float4 cv = cj[q];
                a0 = __builtin_fmaf(xr[q].x, cv.x, a0);
                a1 = __builtin_fmaf(xr[q].y, cv.y, a1);
                a2 = __builtin_fmaf(xr[q].z, cv.z, a2);
                a3 = __builtin_fmaf(xr[q].w, cv.w, a3);
            }
            const float F = sj[j] - 2.0f * ((a0 + a1) + (a2 + a3));
            if (F <= win) {
                float t0 = 0.f, t1 = 0.f;
                #pragma unroll
                for (int q = 0; q < DIM4; ++q) {
                    const float4 cv = cj[q];
                    t0 = __builtin_fmaf(xr[q].x, cv.x, t0);
                    t1 = __builtin_fmaf(xr[q].y, cv.y, t1);
                    t0 = __builtin_fmaf(xr[q].z, cv.z, t0);
                    t1 = __builtin_fmaf(xr[q].w, cv.w, t1);
                }
                float E;
                {
#pragma clang fp contract(off)
                    const float D = t0 + t1;
                    const float u = Tp - 2.0f * D;
                    E = u + sj[j];
                }
                if (E < bestE) { bestE = E; bj = j; }
            }
        }
        lab = bj;
    }
    labels[p] = lab;
}

__global__ __launch_bounds__(256)
void k_hist(const int* __restrict__ labels, int* __restrict__ H)
{
    __shared__ int h[KC];
    for (int i = threadIdx.x; i < KC; i += 256) h[i] = 0;
    __syncthreads();
    const int b = blockIdx.x;
    #pragma unroll
    for (int u = 0; u < 2; ++u)
        atomicAdd(&h[labels[b * CHK + u * 256 + threadIdx.x]], 1);
    __syncthreads();
    for (int i = threadIdx.x; i < KC; i += 256) H[i * NBLK_H + b] = h[i];
}

__global__ __launch_bounds__(128)
void k_scan(const int* __restrict__ H, int* __restrict__ OFFS,
            int* __restrict__ counts, int* __restrict__ cbase)
{
    __shared__ int tot[KC];
    const int j = threadIdx.x;
    if (j < KC) {
        int run = 0;
        for (int b = 0; b < NBLK_H; ++b) { OFFS[j * NBLK_H + b] = run; run += H[j * NBLK_H + b]; }
        tot[j] = run;
    }
    __syncthreads();
    if (j == 0) {
        int base = 0;
        for (int jj = 0; jj < KC; ++jj) { cbase[jj] = base; counts[jj] = tot[jj]; base += tot[jj]; }
    }
}

// stable scatter: serial lane preserves ascending-p order within block
__global__ __launch_bounds__(64)
void k_scatter(const int* __restrict__ labels, const int* __restrict__ OFFS,
               const int* __restrict__ cbase, int* __restrict__ ptidx)
{
    __shared__ int lab[CHK];
    __shared__ int lrank[KC];
    __shared__ int soff[KC];
    const int b = blockIdx.x;
    for (int i = threadIdx.x; i < CHK; i += 64) lab[i] = labels[b * CHK + i];
    for (int i = threadIdx.x; i < KC; i += 64) { lrank[i] = 0; soff[i] = cbase[i] + OFFS[i * NBLK_H + b]; }
    __syncthreads();
    if (threadIdx.x == 0) {
        for (int i = 0; i < CHK; ++i) {
            const int l = lab[i];
            ptidx[soff[l] + lrank[l]++] = b * CHK + i;
        }
    }
}

// exact segment sums: ascending-p sequential f32 adds.
// 16-deep double-buffered REGISTER pipeline (launch_bounds(128,1): no VGPR cap,
// no scratch spill — r24's 40-VGPR spill was the 731us cost).
// Lanes d=0..127 read x[row][d]: one coalesced 512B burst per row.
__global__ __launch_bounds__(128, 1)
void k_update(const float* __restrict__ x, const int* __restrict__ ptidx,
              const int* __restrict__ counts, const int* __restrict__ cbase,
              const float* __restrict__ cold, float* __restrict__ cnew,
              float* __restrict__ csq)
{
    __shared__ int   spt[2][CHK];
    __shared__ float row[DIM];
    const int j = blockIdx.x, d = threadIdx.x;
    const int n = counts[j], base = cbase[j];
    const int nchunks = (n + CHK - 1) / CHK;

    // preload first index chunk
    if (n > 0) {
        const int m0 = min(CHK, n);
        for (int i = d; i < m0; i += 128) spt[0][i] = ptidx[base + i];
    }
    __syncthreads();

    float s = 0.f;
    for (int cc = 0; cc < nchunks; ++cc) {
        const int c0 = cc * CHK;
        const int m  = min(CHK, n - c0);
        const int cb = cc & 1;

        // prefetch next index chunk into the other LDS buffer
        if (cc + 1 < nchunks) {
            const int c1 = (cc + 1) * CHK;
            const int m1 = min(CHK, n - c1);
            for (int i = d; i < m1; i += 128) spt[cb ^ 1][i] = ptidx[base + c1 + i];
        }

        const int nfull = m & ~15;
        float vA[16], vB[16];
        if (nfull >= 16) {
            #pragma unroll
            for (int u = 0; u < 16; ++u) vA[u] = x[(size_t)spt[cb][u] * DIM + d];
        }
        int q = 0;
        while (q * 16 < nfull) {
            if ((q + 1) * 16 < nfull) {
                #pragma unroll
                for (int u = 0; u < 16; ++u) vB[u] = x[(size_t)spt[cb][(q+1)*16+u] * DIM + d];
            }
            {
#pragma clang fp contract(off)
                #pragma unroll
                for (int u = 0; u < 16; ++u) s += vA[u];
            }
            ++q;
            if (q * 16 >= nfull) break;
            if ((q + 1) * 16 < nfull) {
                #pragma unroll
                for (int u = 0; u < 16; ++u) vA[u] = x[(size_t)spt[cb][(q+1)*16+u] * DIM + d];
            }
            {
#pragma clang fp contract(off)
                #pragma unroll
                for (int u = 0; u < 16; ++u) s += vB[u];
            }
            ++q;
        }
        {
#pragma clang fp contract(off)
            for (int t = nfull; t < m; ++t) s += x[(size_t)spt[cb][t] * DIM + d];
        }
        __syncthreads();   // next chunk's spt ready; buffer cb reusable
    }

    const float v = (n > 0) ? (s / fmaxf((float)n, 1.0f)) : cold[j * DIM + d];
    cnew[j * DIM + d] = v;
    row[d] = v;
    __syncthreads();
    if (d == 0) csq[j] = np_sumsq128(row);
}

extern "C" void kernel_launch(void* const* d_in, const int* in_sizes, int n_in,
                              void* d_out, int out_size, void* d_ws, size_t ws_size,
                              hipStream_t stream)
{
    int* labels = (int*)d_out;

    const float* x = nullptr;
    for (int i = 0; i < n_in; ++i)
        if (in_sizes[i] == NPTS * DIM) { x = (const float*)d_in[i]; break; }
    if (!x)                        { k_fill<<<(NPTS+255)/256, 256, 0, stream>>>(labels, NPTS, 2000); return; }
    if (ws_size < (size_t)WS_NEED) { k_fill<<<(NPTS+255)/256, 256, 0, stream>>>(labels, NPTS, 3000); return; }

    char* w = (char*)d_ws;
    float* c_a    = (float*)(w + WS_CA);
    float* c_b    = (float*)(w + WS_CB);
    float* csq    = (float*)(w + WS_CSQ);
    int*   counts = (int*)  (w + WS_CNT);
    int*   cbase  = (int*)  (w + WS_CBASE);
    int*   H      = (int*)  (w + WS_H);
    int*   OFFS   = (int*)  (w + WS_OFFS);
    int*   ptidx  = (int*)  (w + WS_PT);

    k_initc<<<KC, 128, 0, stream>>>(x, c_a, csq);

    float* c_cur = c_a;
    float* c_nxt = c_b;
    for (int it = 0; it < NITERS; ++it) {
        k_assign<<<NPTS / 256, 256, 0, stream>>>(x, c_cur, csq, labels);
        if (it < NITERS - 1) {
            k_hist   <<<NBLK_H, 256, 0, stream>>>(labels, H);
            k_scan   <<<1, 128, 0, stream>>>(H, OFFS, counts, cbase);
            k_scatter<<<NBLK_H, 64, 0, stream>>>(labels, OFFS, cbase, ptidx);
            k_update <<<KC, 128, 0, stream>>>(x, ptidx, counts, cbase, c_cur, c_nxt, csq);
            float* tmp = c_cur; c_cur = c_nxt; c_nxt = tmp;
        }
    }
}